// Round 12
// baseline (122.575 us; speedup 1.0000x reference)
//
#include <hip/hip_runtime.h>
#include <cmath>

// Problem constants (from reference): N=2, Lq=1024, Lk=1024, H=8, d=64, P=1, D=512
#define NB    2
#define LSEQ  1024
#define NH    8
#define HD    64
#define DD    512    // NH*HD
#define FDIM  128    // 2*HD  (cos|sin features)
#define EV    65     // HD + 1 (values + denominator unit column)
#define SEP   80     // padded e-extent of the stored chunk state
#define CHUNK 64
#define NC    16     // LSEQ / CHUNK
#define NBH   16     // NB*NH

// bf16 input buffer segment offsets (elements)
#define XQ_OFF  0
#define XK_OFF  1048576
#define WQ_OFF  2097152
#define WK_OFF  2359296
#define WV_OFF  2621440
#define CVT_TOTAL 2883584

typedef short short8 __attribute__((ext_vector_type(8)));   // 8 bf16 (4 VGPRs)
typedef float floatx4 __attribute__((ext_vector_type(4)));  // MFMA C/D frag
typedef unsigned short ushort;

__device__ __forceinline__ float softplusf(float x) {
  return fmaxf(x, 0.0f) + log1pf(expf(-fabsf(x)));
}

__device__ __forceinline__ ushort f2bf(float f) {
  unsigned u = __float_as_uint(f);
  u += 0x7fffu + ((u >> 16) & 1u);
  return (ushort)(u >> 16);
}

__device__ __forceinline__ short8 cvt8(float4 a, float4 b) {
  short8 r;
  r[0] = (short)f2bf(a.x); r[1] = (short)f2bf(a.y);
  r[2] = (short)f2bf(a.z); r[3] = (short)f2bf(a.w);
  r[4] = (short)f2bf(b.x); r[5] = (short)f2bf(b.y);
  r[6] = (short)f2bf(b.z); r[7] = (short)f2bf(b.w);
  return r;
}

// ---------------------------------------------------------------------------
// K0: one-shot RNE fp32->bf16 conversion of X(query,key) and W(q,k,v).
// Identical rounding to the old in-loop cvt8 -> GEMM inputs bit-identical.
// ---------------------------------------------------------------------------
__global__ __launch_bounds__(256) void k_cvt(
    const float* __restrict__ q, const float* __restrict__ k,
    const float* __restrict__ wq, const float* __restrict__ wk,
    const float* __restrict__ wv, ushort* __restrict__ o)
{
  const int idx = (blockIdx.x * 256 + threadIdx.x) * 8;
  if (idx >= CVT_TOTAL) return;
  const float* src; int off;
  if      (idx < XK_OFF) { src = q;  off = idx; }
  else if (idx < WQ_OFF) { src = k;  off = idx - XK_OFF; }
  else if (idx < WK_OFF) { src = wq; off = idx - WQ_OFF; }
  else if (idx < WV_OFF) { src = wk; off = idx - WK_OFF; }
  else                   { src = wv; off = idx - WV_OFF; }
  const float4 a = *(const float4*)(src + off);
  const float4 b = *(const float4*)(src + off + 4);
  *(short8*)(o + idx) = cvt8(a, b);
}

// ---------------------------------------------------------------------------
// K1 v4: ALL projections, bf16 MFMA, 128x128 tiles, K-slice 64, register
// double-buffered bf16 staging (zero conversions in the hot loop).
// Grid 192: blocks 0..63 = q (16 m-tiles x 4 e-tiles); 64..191 = k/v
// (16 m-tiles x 8 e-tiles: nt 0..3 -> Wk, 4..7 -> Wv).
// Wave = 32 m-rows x 128 e (2x8 accumulator frags).
// ---------------------------------------------------------------------------
__global__ __launch_bounds__(256) void k_proj(
    const ushort* __restrict__ XW, const float* __restrict__ pw,
    const float* __restrict__ pb, const float* __restrict__ pc,
    ushort* __restrict__ Qfb, ushort* __restrict__ Kfb,
    ushort* __restrict__ Vxb)
{
  __shared__ short Al[128][72];   // [m][k] bf16 (18432 B)
  __shared__ short Bl[128][72];   // [e][k] bf16 (18432 B)
  const int b = blockIdx.x;
  int m0, e0, pmode;              // 0 = q, 1 = k, 2 = v
  const ushort *X, *W;
  if (b < 64) {
    m0 = (b >> 2) << 7; e0 = (b & 3) << 7;
    X = XW + XQ_OFF; W = XW + WQ_OFF + (size_t)e0 * DD; pmode = 0;
  } else {
    const int bb = b - 64;
    m0 = (bb >> 3) << 7;
    const int nt = bb & 7;
    e0 = (nt & 3) << 7;
    X = XW + XK_OFF;
    if (nt < 4) { W = XW + WK_OFF + (size_t)e0 * DD; pmode = 1; }
    else        { W = XW + WV_OFF + (size_t)e0 * DD; pmode = 2; }
  }
  const int tid  = threadIdx.x;
  const int r    = tid >> 1;               // staging row 0..127
  const int ko   = (tid & 1) << 5;         // 0 or 32 shorts
  const int wave = tid >> 6, lane = tid & 63;
  const int quad = lane >> 4, lm = lane & 15;
  const ushort* Ag = X + (size_t)(m0 + r) * DD + ko;
  const ushort* Bg = W + (size_t)r * DD + ko;
  short8 a[4], bs[4];
#pragma unroll
  for (int u = 0; u < 4; ++u) {
    a[u]  = *(const short8*)(Ag + (u << 3));
    bs[u] = *(const short8*)(Bg + (u << 3));
  }
  floatx4 acc[2][8] = {};
  for (int k0 = 0; k0 < DD; k0 += 64) {
    __syncthreads();
#pragma unroll
    for (int u = 0; u < 4; ++u) {
      *(short8*)&Al[r][ko + (u << 3)] = a[u];
      *(short8*)&Bl[r][ko + (u << 3)] = bs[u];
    }
    __syncthreads();
    if (k0 + 64 < DD) {
#pragma unroll
      for (int u = 0; u < 4; ++u) {
        a[u]  = *(const short8*)(Ag + k0 + 64 + (u << 3));
        bs[u] = *(const short8*)(Bg + k0 + 64 + (u << 3));
      }
    }
#pragma unroll
    for (int ks = 0; ks < 2; ++ks) {
      const short8 a0 = *(const short8*)&Al[(wave << 5) + lm][(ks << 5) + (quad << 3)];
      const short8 a1 = *(const short8*)&Al[(wave << 5) + 16 + lm][(ks << 5) + (quad << 3)];
#pragma unroll
      for (int t = 0; t < 8; ++t) {
        const short8 bf = *(const short8*)&Bl[(t << 4) + lm][(ks << 5) + (quad << 3)];
        acc[0][t] = __builtin_amdgcn_mfma_f32_16x16x32_bf16(a0, bf, acc[0][t], 0, 0, 0);
        acc[1][t] = __builtin_amdgcn_mfma_f32_16x16x32_bf16(a1, bf, acc[1][t], 0, 0, 0);
      }
    }
  }
  // epilogue (same math/rounding as before, just 4x outputs per thread)
#pragma unroll
  for (int t = 0; t < 8; ++t) {
    const int e = e0 + (t << 4) + lm;
    const int h = e >> 6, jj = e & 63;
    if (pmode == 2) {
#pragma unroll
      for (int mi = 0; mi < 2; ++mi)
#pragma unroll
        for (int rg = 0; rg < 4; ++rg) {
          const int m = m0 + (wave << 5) + (mi << 4) + (quad << 2) + rg;
          const int n = m >> 10, l = m & 1023;
          Vxb[((size_t)(n * NH + h) * LSEQ + l) * HD + jj] = f2bf(acc[mi][t][rg]);
        }
    } else {
      const float pwv = pw[e];
      const float pbv = (pmode == 0) ? pb[e] : 0.0f;
      const float pcv = (pmode == 0) ? pc[e] : 1.0f;
      ushort* base = (pmode == 0) ? Qfb : Kfb;
#pragma unroll
      for (int mi = 0; mi < 2; ++mi)
#pragma unroll
        for (int rg = 0; rg < 4; ++rg) {
          const int m = m0 + (wave << 5) + (mi << 4) + (quad << 2) + rg;
          const int n = m >> 10, l = m & 1023;
          const float v = softplusf(acc[mi][t][rg]) * pcv;
          const float ang = fmaf((float)l, pwv, pbv);
          ushort* dst = &base[((size_t)(n * NH + h) * LSEQ + l) * FDIM + jj];
          dst[0]  = f2bf(v * __cosf(ang));
          dst[64] = f2bf(v * __sinf(ang));
        }
    }
  }
}

// ---------------------------------------------------------------------------
// K2: per-chunk state sums on bf16 MFMA, stored TRANSPOSED + padded fp32:
// S^T[bh*NC+c][e=0..79][f=0..127]. Grid 512: blk = bh*32 + c*2 + fh.
// ---------------------------------------------------------------------------
__global__ __launch_bounds__(256) void k_chunk_sums(
    const ushort* __restrict__ Kfb, const ushort* __restrict__ Vxb,
    float* __restrict__ S)
{
  const int blk = blockIdx.x;
  const int bh  = blk >> 5;
  const int c   = (blk >> 1) & (NC - 1);
  const int fh  = blk & 1;
  const int f0  = fh << 6;
  const int t0  = c * CHUNK;
  const int tid  = threadIdx.x;
  const int wave = tid >> 6, lane = tid & 63;
  const int quad = lane >> 4, lm = lane & 15;

  __shared__ short KT[64][72];   // [f-f0][t] bf16  9216 B
  __shared__ short VT[80][72];   // [e][t]    bf16 11520 B

  for (int i = tid; i < 64 * 8; i += 256) {
    const int t = i & 63, f8 = (i >> 6) << 3;
    const short8 k8 = *(const short8*)&Kfb[((size_t)bh * LSEQ + t0 + t) * FDIM + f0 + f8];
#pragma unroll
    for (int u = 0; u < 8; ++u) KT[f8 + u][t] = k8[u];
  }
  for (int i = tid; i < 64 * 8; i += 256) {
    const int t = i & 63, e8 = (i >> 6) << 3;
    const short8 v8 = *(const short8*)&Vxb[((size_t)bh * LSEQ + t0 + t) * HD + e8];
#pragma unroll
    for (int u = 0; u < 8; ++u) VT[e8 + u][t] = v8[u];
  }
  if (tid < CHUNK) VT[64][tid] = (short)0x3F80;   // bf16 1.0
  __syncthreads();

  short8 aK[2];
#pragma unroll
  for (int ks = 0; ks < 2; ++ks)
    aK[ks] = *(const short8*)&KT[(wave << 4) + lm][(quad << 3) + (ks << 5)];
  floatx4 acc[5] = {};
#pragma unroll
  for (int nt = 0; nt < 5; ++nt)
#pragma unroll
    for (int ks = 0; ks < 2; ++ks) {
      const short8 bf = *(const short8*)&VT[(nt << 4) + lm][(quad << 3) + (ks << 5)];
      acc[nt] = __builtin_amdgcn_mfma_f32_16x16x32_bf16(aK[ks], bf, acc[nt], 0, 0, 0);
    }

  float* Sb = &S[(size_t)(bh * NC + c) * SEP * FDIM];
#pragma unroll
  for (int nt = 0; nt < 4; ++nt)
#pragma unroll
    for (int rg = 0; rg < 4; ++rg) {
      const int f = f0 + (wave << 4) + (quad << 2) + rg;
      Sb[((nt << 4) + lm) * FDIM + f] = acc[nt][rg];
    }
  if (lm == 0) {
#pragma unroll
    for (int rg = 0; rg < 4; ++rg) {
      const int f = f0 + (wave << 4) + (quad << 2) + rg;
      Sb[64 * FDIM + f] = acc[4][rg];
    }
  }
}

// ---------------------------------------------------------------------------
// K3: exclusive prefix scan over the NC chunk states per bh (ILP-16 loads,
// fp32 accumulate, bf16 B-frag-layout output). Grid NBH*13.
// ---------------------------------------------------------------------------
__global__ __launch_bounds__(256) void k_scan(
    const float* __restrict__ S, ushort* __restrict__ PTb)
{
  const int bh = blockIdx.x / 13;
  const int eg = blockIdx.x % 13;          // 13 groups of 5 e-rows (65 total)
  const size_t cs = (size_t)SEP * FDIM;    // chunk stride (elements)
  const float* Sg = S + (size_t)bh * NC * cs;
  ushort* Pg = PTb + (size_t)bh * NC * cs;
  for (int i = threadIdx.x; i < 5 * FDIM; i += 256) {
    const int e = eg * 5 + (i >> 7);
    const int f = i & 127;
    const int off = e * FDIM + f;
    float v[NC];
#pragma unroll
    for (int c = 0; c < NC; ++c) v[c] = Sg[(size_t)c * cs + off];
    float s = 0.0f;
#pragma unroll
    for (int c = 0; c < NC; ++c) {
      Pg[(size_t)c * cs + off] = f2bf(s);
      s += v[c];
    }
  }
}

// ---------------------------------------------------------------------------
// K4: per-chunk output, all three matmuls on bf16 MFMA (fp32 accumulate).
// Conversion-free staging throughout.
// ---------------------------------------------------------------------------
__global__ __launch_bounds__(256) void k_chunk_out(
    const ushort* __restrict__ Qfb, const ushort* __restrict__ Kfb,
    const ushort* __restrict__ Vxb, const ushort* __restrict__ PTb,
    float* __restrict__ Out)
{
  const int c  = blockIdx.x & (NC - 1);
  const int bh = blockIdx.x >> 4;
  const int n  = bh >> 3, h = bh & 7;
  const int t0 = c * CHUNK;
  const int tid  = threadIdx.x;
  const int wave = tid >> 6, lane = tid & 63;
  const int quad = lane >> 4, lm = lane & 15;

  __shared__ short QL[64][128];    // [t][f] bf16  16384 B
  __shared__ short KL[64][128];    // [t][f] bf16  16384 B
  __shared__ short ScL[64][72];    // [m][t] bf16   9216 B
  __shared__ short PT[80][136];    // [e][f] bf16  21760 B
  __shared__ short VT[80][72];     // [e][t] bf16  11520 B
  __shared__ float DenL[64];       //                256 B

  const ushort* Qg = &Qfb[((size_t)bh * LSEQ + t0) * FDIM];
  const ushort* Kg = &Kfb[((size_t)bh * LSEQ + t0) * FDIM];
  for (int i = tid; i < 64 * 16; i += 256) {
    const int r = i >> 4, f8 = (i & 15) << 3;
    *(short8*)&QL[r][f8] = *(const short8*)&Qg[r * FDIM + f8];
    *(short8*)&KL[r][f8] = *(const short8*)&Kg[r * FDIM + f8];
  }
  {
    const ushort* Pg = &PTb[(size_t)(bh * NC + c) * SEP * FDIM];
    for (int i = tid; i < 65 * 16; i += 256) {
      const int e = i >> 4, f8 = (i & 15) << 3;
      *(short8*)&PT[e][f8] = *(const short8*)&Pg[e * FDIM + f8];
    }
  }
  for (int i = tid; i < 64 * 8; i += 256) {
    const int t = i & 63, e8 = (i >> 6) << 3;
    const short8 v8 = *(const short8*)&Vxb[((size_t)bh * LSEQ + t0 + t) * HD + e8];
#pragma unroll
    for (int u = 0; u < 8; ++u) VT[e8 + u][t] = v8[u];
  }
  if (tid < CHUNK) VT[64][tid] = (short)0x3F80;   // bf16 1.0
  __syncthreads();

  short8 aQ[4];
#pragma unroll
  for (int ks = 0; ks < 4; ++ks)
    aQ[ks] = *(const short8*)&QL[(wave << 4) + lm][(quad << 3) + (ks << 5)];

  // phase 1: scores
  floatx4 accS[4] = {};
#pragma unroll
  for (int nt = 0; nt < 4; ++nt)
#pragma unroll
    for (int ks = 0; ks < 4; ++ks) {
      const short8 b = *(const short8*)&KL[(nt << 4) + lm][(quad << 3) + (ks << 5)];
      accS[nt] = __builtin_amdgcn_mfma_f32_16x16x32_bf16(aQ[ks], b, accS[nt], 0, 0, 0);
    }
#pragma unroll
  for (int nt = 0; nt < 4; ++nt)
#pragma unroll
    for (int rg = 0; rg < 4; ++rg) {
      const int m = (wave << 4) + (quad << 2) + rg;
      const int t = (nt << 4) + lm;
      ScL[m][t] = (short)((t <= m) ? f2bf(accS[nt][rg]) : 0);
    }

  // phase 2: num = Q @ P (+den col at e=64)
  floatx4 accN[5] = {};
#pragma unroll
  for (int nt = 0; nt < 5; ++nt)
#pragma unroll
    for (int ks = 0; ks < 4; ++ks) {
      const short8 b = *(const short8*)&PT[(nt << 4) + lm][(quad << 3) + (ks << 5)];
      accN[nt] = __builtin_amdgcn_mfma_f32_16x16x32_bf16(aQ[ks], b, accN[nt], 0, 0, 0);
    }

  // phase 3: PV = Sc @ Vext (+rowsum col); same-wave ScL access, no barrier
  short8 aS[2];
#pragma unroll
  for (int ks = 0; ks < 2; ++ks)
    aS[ks] = *(const short8*)&ScL[(wave << 4) + lm][(quad << 3) + (ks << 5)];
  floatx4 accV[5] = {};
#pragma unroll
  for (int nt = 0; nt < 5; ++nt)
#pragma unroll
    for (int ks = 0; ks < 2; ++ks) {
      const short8 b = *(const short8*)&VT[(nt << 4) + lm][(quad << 3) + (ks << 5)];
      accV[nt] = __builtin_amdgcn_mfma_f32_16x16x32_bf16(aS[ks], b, accV[nt], 0, 0, 0);
    }

  if (lm == 0) {
#pragma unroll
    for (int rg = 0; rg < 4; ++rg)
      DenL[(wave << 4) + (quad << 2) + rg] = accN[4][rg] + accV[4][rg];
  }

#pragma unroll
  for (int rg = 0; rg < 4; ++rg) {
    const int m = (wave << 4) + (quad << 2) + rg;
    const float rden = 1.0f / DenL[m];
    const int l = t0 + m;
#pragma unroll
    for (int nt = 0; nt < 4; ++nt) {
      const float val = (accN[nt][rg] + accV[nt][rg]) * rden;
      Out[((size_t)(n * LSEQ + l)) * DD + h * HD + (nt << 4) + lm] = val;
    }
  }
}

// ---------------------------------------------------------------------------
extern "C" void kernel_launch(void* const* d_in, const int* in_sizes, int n_in,
                              void* d_out, int out_size, void* d_ws, size_t ws_size,
                              hipStream_t stream) {
  (void)in_sizes; (void)n_in; (void)out_size; (void)ws_size;
  const float* query  = (const float*)d_in[0];
  const float* keyseq = (const float*)d_in[1];
  const float* Wq     = (const float*)d_in[2];
  const float* Wk     = (const float*)d_in[3];
  const float* Wv     = (const float*)d_in[4];
  const float* pc     = (const float*)d_in[5];  // position_coeffs (H,d)
  const float* pw     = (const float*)d_in[6];  // position_weight (H,d,1)
  const float* pb     = (const float*)d_in[7];  // position_bias (H,d)
  float* out = (float*)d_out;

  // workspace layout
  ushort* XWb = (ushort*)d_ws;                            // 5.77 MB (bf16 X+W)
  ushort* Qfb = XWb + CVT_TOTAL;                          // 4 MB
  ushort* Kfb = Qfb + (size_t)NBH * LSEQ * FDIM;          // 4 MB
  ushort* Vxb = Kfb + (size_t)NBH * LSEQ * FDIM;          // 2 MB
  float*  S   = (float*)(Vxb + (size_t)NBH * LSEQ * HD);  // 10.5 MB
  ushort* PTb = (ushort*)(S + (size_t)NBH * NC * SEP * FDIM); // 5.2 MB

  k_cvt       <<<(CVT_TOTAL / 8 + 255) / 256, 256, 0, stream>>>(query, keyseq, Wq, Wk, Wv, XWb);
  k_proj      <<<192,          256, 0, stream>>>(XWb, pw, pb, pc, Qfb, Kfb, Vxb);
  k_chunk_sums<<<NBH * NC * 2, 256, 0, stream>>>(Kfb, Vxb, S);
  k_scan      <<<NBH * 13,     256, 0, stream>>>(S, PTb);
  k_chunk_out <<<NBH * NC,     256, 0, stream>>>(Qfb, Kfb, Vxb, PTb, out);
}

// Round 13
// 112.085 us; speedup vs baseline: 1.0936x; 1.0936x over previous
//
#include <hip/hip_runtime.h>
#include <cmath>

// Problem constants (from reference): N=2, Lq=1024, Lk=1024, H=8, d=64, P=1, D=512
#define NB    2
#define LSEQ  1024
#define NH    8
#define HD    64
#define DD    512    // NH*HD
#define FDIM  128    // 2*HD  (cos|sin features)
#define EV    65     // HD + 1 (values + denominator unit column)
#define SEP   80     // padded e-extent of the stored chunk state
#define CHUNK 64
#define NC    16     // LSEQ / CHUNK
#define NBH   16     // NB*NH

typedef short short8 __attribute__((ext_vector_type(8)));   // 8 bf16 (4 VGPRs)
typedef float floatx4 __attribute__((ext_vector_type(4)));  // MFMA C/D frag
typedef unsigned short ushort;

__device__ __forceinline__ float softplusf(float x) {
  return fmaxf(x, 0.0f) + log1pf(expf(-fabsf(x)));
}

__device__ __forceinline__ ushort f2bf(float f) {
  unsigned u = __float_as_uint(f);
  u += 0x7fffu + ((u >> 16) & 1u);
  return (ushort)(u >> 16);
}

__device__ __forceinline__ short8 cvt8(float4 a, float4 b) {
  short8 r;
  r[0] = (short)f2bf(a.x); r[1] = (short)f2bf(a.y);
  r[2] = (short)f2bf(a.z); r[3] = (short)f2bf(a.w);
  r[4] = (short)f2bf(b.x); r[5] = (short)f2bf(b.y);
  r[6] = (short)f2bf(b.z); r[7] = (short)f2bf(b.w);
  return r;
}

// ---------------------------------------------------------------------------
// K1: ALL projections, bf16 MFMA, K-slice 64, 64x64 tiles, 768 blocks
// (3 blocks/CU). NOW LDS double-buffered: ONE barrier per K-slice; next
// slice's global loads + cvt/stores overlap the current slice's MFMA.
// Outputs bf16 row layouts (unchanged from the 112.6 µs config).
// ---------------------------------------------------------------------------
__global__ __launch_bounds__(256) void k_proj(
    const float* __restrict__ Xq, const float* __restrict__ Xkv,
    const float* __restrict__ Wq, const float* __restrict__ Wk,
    const float* __restrict__ Wv, const float* __restrict__ pw,
    const float* __restrict__ pb, const float* __restrict__ pc,
    ushort* __restrict__ Qfb, ushort* __restrict__ Kfb,
    ushort* __restrict__ Vxb)
{
  __shared__ short Al[2][64][72];   // [buf][m][k] bf16 (18432 B)
  __shared__ short Bl[2][64][72];   // [buf][e][k] bf16 (18432 B)
  const int b = blockIdx.x;
  int m0, e0, pmode;             // 0 = q, 1 = k, 2 = v
  const float *X, *W;
  if (b < 256) {
    m0 = (b >> 3) << 6; e0 = (b & 7) << 6;
    X = Xq; W = Wq + (size_t)e0 * DD; pmode = 0;
  } else {
    const int bb = b - 256;
    m0 = (bb >> 4) << 6;
    const int nt = bb & 15;
    e0 = (nt & 7) << 6;
    X = Xkv;
    if (nt < 8) { W = Wk + (size_t)e0 * DD; pmode = 1; }
    else        { W = Wv + (size_t)e0 * DD; pmode = 2; }
  }
  const int tid  = threadIdx.x;
  const int r    = tid >> 2;               // staging row 0..63
  const int ko   = (tid & 3) << 4;         // 0,16,32,48 shorts
  const int wave = tid >> 6, lane = tid & 63;
  const int quad = lane >> 4, lm = lane & 15;
  const float* Ag = X + (size_t)(m0 + r) * DD + ko;
  const float* Bg = W + (size_t)r * DD + ko;
  float4 a[4], bb4[4];
#pragma unroll
  for (int u = 0; u < 4; ++u) {
    a[u]   = *(const float4*)(Ag + (u << 2));
    bb4[u] = *(const float4*)(Bg + (u << 2));
  }
  // prologue: stage slice 0 into buffer 0
  *(short8*)&Al[0][r][ko]     = cvt8(a[0], a[1]);
  *(short8*)&Al[0][r][ko + 8] = cvt8(a[2], a[3]);
  *(short8*)&Bl[0][r][ko]     = cvt8(bb4[0], bb4[1]);
  *(short8*)&Bl[0][r][ko + 8] = cvt8(bb4[2], bb4[3]);
  __syncthreads();

  floatx4 acc[4] = {};
  for (int k0 = 0; k0 < DD; k0 += 64) {
    const int cur  = (k0 >> 6) & 1;
    const bool more = (k0 + 64 < DD);
    if (more) {
#pragma unroll
      for (int u = 0; u < 4; ++u) {
        a[u]   = *(const float4*)(Ag + k0 + 64 + (u << 2));
        bb4[u] = *(const float4*)(Bg + k0 + 64 + (u << 2));
      }
    }
#pragma unroll
    for (int ks = 0; ks < 2; ++ks) {
      const short8 af = *(const short8*)&Al[cur][(wave << 4) + lm][(quad << 3) + (ks << 5)];
#pragma unroll
      for (int t = 0; t < 4; ++t) {
        const short8 bf = *(const short8*)&Bl[cur][(t << 4) + lm][(quad << 3) + (ks << 5)];
        acc[t] = __builtin_amdgcn_mfma_f32_16x16x32_bf16(af, bf, acc[t], 0, 0, 0);
      }
    }
    if (more) {
      const int nxt = cur ^ 1;
      *(short8*)&Al[nxt][r][ko]     = cvt8(a[0], a[1]);
      *(short8*)&Al[nxt][r][ko + 8] = cvt8(a[2], a[3]);
      *(short8*)&Bl[nxt][r][ko]     = cvt8(bb4[0], bb4[1]);
      *(short8*)&Bl[nxt][r][ko + 8] = cvt8(bb4[2], bb4[3]);
    }
    __syncthreads();   // single barrier per slice (2 buffers make it safe)
  }
#pragma unroll
  for (int t = 0; t < 4; ++t) {
    const int e = e0 + (t << 4) + lm;
    const int h = e >> 6, jj = e & 63;
    if (pmode == 2) {
#pragma unroll
      for (int rg = 0; rg < 4; ++rg) {
        const int m = m0 + (wave << 4) + (quad << 2) + rg;
        const int n = m >> 10, l = m & 1023;
        Vxb[((size_t)(n * NH + h) * LSEQ + l) * HD + jj] = f2bf(acc[t][rg]);
      }
    } else {
      const float pwv = pw[e];
      const float pbv = (pmode == 0) ? pb[e] : 0.0f;
      const float pcv = (pmode == 0) ? pc[e] : 1.0f;
      ushort* base = (pmode == 0) ? Qfb : Kfb;
#pragma unroll
      for (int rg = 0; rg < 4; ++rg) {
        const int m = m0 + (wave << 4) + (quad << 2) + rg;
        const int n = m >> 10, l = m & 1023;
        const float v = softplusf(acc[t][rg]) * pcv;
        const float ang = fmaf((float)l, pwv, pbv);
        ushort* dst = &base[((size_t)(n * NH + h) * LSEQ + l) * FDIM + jj];
        dst[0]  = f2bf(v * __cosf(ang));
        dst[64] = f2bf(v * __sinf(ang));
      }
    }
  }
}

// ---------------------------------------------------------------------------
// K2: per-chunk state sums on bf16 MFMA, stored TRANSPOSED + padded fp32:
// S^T[bh*NC+c][e=0..79][f=0..127]. Grid 512: blk = bh*32 + c*2 + fh.
// ---------------------------------------------------------------------------
__global__ __launch_bounds__(256) void k_chunk_sums(
    const ushort* __restrict__ Kfb, const ushort* __restrict__ Vxb,
    float* __restrict__ S)
{
  const int blk = blockIdx.x;
  const int bh  = blk >> 5;
  const int c   = (blk >> 1) & (NC - 1);
  const int fh  = blk & 1;
  const int f0  = fh << 6;
  const int t0  = c * CHUNK;
  const int tid  = threadIdx.x;
  const int wave = tid >> 6, lane = tid & 63;
  const int quad = lane >> 4, lm = lane & 15;

  __shared__ short KT[64][72];   // [f-f0][t] bf16  9216 B
  __shared__ short VT[80][72];   // [e][t]    bf16 11520 B

  for (int i = tid; i < 64 * 8; i += 256) {
    const int t = i & 63, f8 = (i >> 6) << 3;
    const short8 k8 = *(const short8*)&Kfb[((size_t)bh * LSEQ + t0 + t) * FDIM + f0 + f8];
#pragma unroll
    for (int u = 0; u < 8; ++u) KT[f8 + u][t] = k8[u];
  }
  for (int i = tid; i < 64 * 8; i += 256) {
    const int t = i & 63, e8 = (i >> 6) << 3;
    const short8 v8 = *(const short8*)&Vxb[((size_t)bh * LSEQ + t0 + t) * HD + e8];
#pragma unroll
    for (int u = 0; u < 8; ++u) VT[e8 + u][t] = v8[u];
  }
  if (tid < CHUNK) VT[64][tid] = (short)0x3F80;   // bf16 1.0
  __syncthreads();

  short8 aK[2];
#pragma unroll
  for (int ks = 0; ks < 2; ++ks)
    aK[ks] = *(const short8*)&KT[(wave << 4) + lm][(quad << 3) + (ks << 5)];
  floatx4 acc[5] = {};
#pragma unroll
  for (int nt = 0; nt < 5; ++nt)
#pragma unroll
    for (int ks = 0; ks < 2; ++ks) {
      const short8 bf = *(const short8*)&VT[(nt << 4) + lm][(quad << 3) + (ks << 5)];
      acc[nt] = __builtin_amdgcn_mfma_f32_16x16x32_bf16(aK[ks], bf, acc[nt], 0, 0, 0);
    }

  float* Sb = &S[(size_t)(bh * NC + c) * SEP * FDIM];
#pragma unroll
  for (int nt = 0; nt < 4; ++nt)
#pragma unroll
    for (int rg = 0; rg < 4; ++rg) {
      const int f = f0 + (wave << 4) + (quad << 2) + rg;
      Sb[((nt << 4) + lm) * FDIM + f] = acc[nt][rg];
    }
  if (lm == 0) {
#pragma unroll
    for (int rg = 0; rg < 4; ++rg) {
      const int f = f0 + (wave << 4) + (quad << 2) + rg;
      Sb[64 * FDIM + f] = acc[4][rg];
    }
  }
}

// ---------------------------------------------------------------------------
// K3: exclusive prefix scan over the NC chunk states per bh (ILP-16 loads,
// fp32 accumulate, bf16 B-frag-layout output). Grid NBH*13.
// ---------------------------------------------------------------------------
__global__ __launch_bounds__(256) void k_scan(
    const float* __restrict__ S, ushort* __restrict__ PTb)
{
  const int bh = blockIdx.x / 13;
  const int eg = blockIdx.x % 13;          // 13 groups of 5 e-rows (65 total)
  const size_t cs = (size_t)SEP * FDIM;    // chunk stride (elements)
  const float* Sg = S + (size_t)bh * NC * cs;
  ushort* Pg = PTb + (size_t)bh * NC * cs;
  for (int i = threadIdx.x; i < 5 * FDIM; i += 256) {
    const int e = eg * 5 + (i >> 7);
    const int f = i & 127;
    const int off = e * FDIM + f;
    float v[NC];
#pragma unroll
    for (int c = 0; c < NC; ++c) v[c] = Sg[(size_t)c * cs + off];
    float s = 0.0f;
#pragma unroll
    for (int c = 0; c < NC; ++c) {
      Pg[(size_t)c * cs + off] = f2bf(s);
      s += v[c];
    }
  }
}

// ---------------------------------------------------------------------------
// K4: per-chunk output, all three matmuls on bf16 MFMA (fp32 accumulate).
// Conversion-free staging throughout.
// ---------------------------------------------------------------------------
__global__ __launch_bounds__(256) void k_chunk_out(
    const ushort* __restrict__ Qfb, const ushort* __restrict__ Kfb,
    const ushort* __restrict__ Vxb, const ushort* __restrict__ PTb,
    float* __restrict__ Out)
{
  const int c  = blockIdx.x & (NC - 1);
  const int bh = blockIdx.x >> 4;
  const int n  = bh >> 3, h = bh & 7;
  const int t0 = c * CHUNK;
  const int tid  = threadIdx.x;
  const int wave = tid >> 6, lane = tid & 63;
  const int quad = lane >> 4, lm = lane & 15;

  __shared__ short QL[64][128];    // [t][f] bf16  16384 B
  __shared__ short KL[64][128];    // [t][f] bf16  16384 B
  __shared__ short ScL[64][72];    // [m][t] bf16   9216 B
  __shared__ short PT[80][136];    // [e][f] bf16  21760 B
  __shared__ short VT[80][72];     // [e][t] bf16  11520 B
  __shared__ float DenL[64];       //                256 B

  const ushort* Qg = &Qfb[((size_t)bh * LSEQ + t0) * FDIM];
  const ushort* Kg = &Kfb[((size_t)bh * LSEQ + t0) * FDIM];
  for (int i = tid; i < 64 * 16; i += 256) {
    const int r = i >> 4, f8 = (i & 15) << 3;
    *(short8*)&QL[r][f8] = *(const short8*)&Qg[r * FDIM + f8];
    *(short8*)&KL[r][f8] = *(const short8*)&Kg[r * FDIM + f8];
  }
  {
    const ushort* Pg = &PTb[(size_t)(bh * NC + c) * SEP * FDIM];
    for (int i = tid; i < 65 * 16; i += 256) {
      const int e = i >> 4, f8 = (i & 15) << 3;
      *(short8*)&PT[e][f8] = *(const short8*)&Pg[e * FDIM + f8];
    }
  }
  for (int i = tid; i < 64 * 8; i += 256) {
    const int t = i & 63, e8 = (i >> 6) << 3;
    const short8 v8 = *(const short8*)&Vxb[((size_t)bh * LSEQ + t0 + t) * HD + e8];
#pragma unroll
    for (int u = 0; u < 8; ++u) VT[e8 + u][t] = v8[u];
  }
  if (tid < CHUNK) VT[64][tid] = (short)0x3F80;   // bf16 1.0
  __syncthreads();

  short8 aQ[4];
#pragma unroll
  for (int ks = 0; ks < 4; ++ks)
    aQ[ks] = *(const short8*)&QL[(wave << 4) + lm][(quad << 3) + (ks << 5)];

  // phase 1: scores
  floatx4 accS[4] = {};
#pragma unroll
  for (int nt = 0; nt < 4; ++nt)
#pragma unroll
    for (int ks = 0; ks < 4; ++ks) {
      const short8 b = *(const short8*)&KL[(nt << 4) + lm][(quad << 3) + (ks << 5)];
      accS[nt] = __builtin_amdgcn_mfma_f32_16x16x32_bf16(aQ[ks], b, accS[nt], 0, 0, 0);
    }
#pragma unroll
  for (int nt = 0; nt < 4; ++nt)
#pragma unroll
    for (int rg = 0; rg < 4; ++rg) {
      const int m = (wave << 4) + (quad << 2) + rg;
      const int t = (nt << 4) + lm;
      ScL[m][t] = (short)((t <= m) ? f2bf(accS[nt][rg]) : 0);
    }

  // phase 2: num = Q @ P (+den col at e=64)
  floatx4 accN[5] = {};
#pragma unroll
  for (int nt = 0; nt < 5; ++nt)
#pragma unroll
    for (int ks = 0; ks < 4; ++ks) {
      const short8 b = *(const short8*)&PT[(nt << 4) + lm][(quad << 3) + (ks << 5)];
      accN[nt] = __builtin_amdgcn_mfma_f32_16x16x32_bf16(aQ[ks], b, accN[nt], 0, 0, 0);
    }

  // phase 3: PV = Sc @ Vext (+rowsum col); same-wave ScL access, no barrier
  short8 aS[2];
#pragma unroll
  for (int ks = 0; ks < 2; ++ks)
    aS[ks] = *(const short8*)&ScL[(wave << 4) + lm][(quad << 3) + (ks << 5)];
  floatx4 accV[5] = {};
#pragma unroll
  for (int nt = 0; nt < 5; ++nt)
#pragma unroll
    for (int ks = 0; ks < 2; ++ks) {
      const short8 b = *(const short8*)&VT[(nt << 4) + lm][(quad << 3) + (ks << 5)];
      accV[nt] = __builtin_amdgcn_mfma_f32_16x16x32_bf16(aS[ks], b, accV[nt], 0, 0, 0);
    }

  if (lm == 0) {
#pragma unroll
    for (int rg = 0; rg < 4; ++rg)
      DenL[(wave << 4) + (quad << 2) + rg] = accN[4][rg] + accV[4][rg];
  }

#pragma unroll
  for (int rg = 0; rg < 4; ++rg) {
    const int m = (wave << 4) + (quad << 2) + rg;
    const float rden = 1.0f / DenL[m];
    const int l = t0 + m;
#pragma unroll
    for (int nt = 0; nt < 4; ++nt) {
      const float val = (accN[nt][rg] + accV[nt][rg]) * rden;
      Out[((size_t)(n * LSEQ + l)) * DD + h * HD + (nt << 4) + lm] = val;
    }
  }
}

// ---------------------------------------------------------------------------
extern "C" void kernel_launch(void* const* d_in, const int* in_sizes, int n_in,
                              void* d_out, int out_size, void* d_ws, size_t ws_size,
                              hipStream_t stream) {
  (void)in_sizes; (void)n_in; (void)out_size; (void)ws_size;
  const float* query  = (const float*)d_in[0];
  const float* keyseq = (const float*)d_in[1];
  const float* Wq     = (const float*)d_in[2];
  const float* Wk     = (const float*)d_in[3];
  const float* Wv     = (const float*)d_in[4];
  const float* pc     = (const float*)d_in[5];  // position_coeffs (H,d)
  const float* pw     = (const float*)d_in[6];  // position_weight (H,d,1)
  const float* pb     = (const float*)d_in[7];  // position_bias (H,d)
  float* out = (float*)d_out;

  // workspace: bf16 intermediates (row layouts), fp32 chunk states, bf16 prefix
  ushort* Qfb = (ushort*)d_ws;                            // 4 MB
  ushort* Kfb = Qfb + (size_t)NBH * LSEQ * FDIM;          // 4 MB
  ushort* Vxb = Kfb + (size_t)NBH * LSEQ * FDIM;          // 2 MB
  float*  S   = (float*)(Vxb + (size_t)NBH * LSEQ * HD);  // 10.5 MB
  ushort* PTb = (ushort*)(S + (size_t)NBH * NC * SEP * FDIM); // 5.2 MB

  k_proj      <<<768,          256, 0, stream>>>(query, keyseq, Wq, Wk, Wv, pw, pb, pc, Qfb, Kfb, Vxb);
  k_chunk_sums<<<NBH * NC * 2, 256, 0, stream>>>(Kfb, Vxb, S);
  k_scan      <<<NBH * 13,     256, 0, stream>>>(S, PTb);
  k_chunk_out <<<NBH * NC,     256, 0, stream>>>(Qfb, Kfb, Vxb, PTb, out);
}